// Round 5
// baseline (1086.518 us; speedup 1.0000x reference)
//
#include <hip/hip_runtime.h>

typedef _Float16 half8 __attribute__((ext_vector_type(8)));
typedef float f32x4 __attribute__((ext_vector_type(4)));

__device__ __forceinline__ unsigned short f2h(float f) {
    _Float16 h = (_Float16)f;
    return __builtin_bit_cast(unsigned short, h);
}
__device__ __forceinline__ float h2f(unsigned short u) {
    return (float)__builtin_bit_cast(_Float16, u);
}

// async global->LDS, 16 B per lane; LDS dest must be linear (base + lane*16)
__device__ __forceinline__ void lds_load16(const uint4* g, uint4* l) {
    __builtin_amdgcn_global_load_lds(
        (const __attribute__((address_space(1))) unsigned int*)g,
        (__attribute__((address_space(3))) unsigned int*)l, 16, 0, 0);
}

// ---- weight transform: OIHW fp32 -> [ck][pos][oct(ci/8)][co][ci&7] fp16 ----
__global__ void wprep_k(const float* __restrict__ src, unsigned short* __restrict__ dst,
                        int Cout, int Cin, int total)
{
    int t = blockIdx.x * 256 + threadIdx.x;
    if (t >= total) return;
    int j = t & 7; int r = t >> 3;
    int co = r % Cout; r /= Cout;
    int oct = r & 3; r >>= 2;
    int pos = r % 9; int ck = r / 9;
    int ci = ck * 32 + oct * 8 + j;
    dst[t] = f2h(src[((size_t)co * Cin + ci) * 9 + pos]);
}

// ---- fc weight transpose: fcw[f][k] -> fcwT[k][f] (512 x 49) ----
__global__ void fct_k(const float* __restrict__ src, float* __restrict__ dst)
{
    int t = blockIdx.x * 256 + threadIdx.x;
    if (t >= 49 * 512) return;
    int k = t >> 9, f = t & 511;
    dst[t] = src[f * 49 + k];
}

// ---- MFMA conv3x3 SAME, NHWC fp16, fp32 accum; 2D tiles, async staging ----
template<int BM, int TW, int TH, int LW, int UP>
__global__ __launch_bounds__(256, 2) void convm2_k(
    const uint4* __restrict__ in1, int C1g,
    const uint4* __restrict__ in2, int C2g,
    const uint4* __restrict__ wt,
    const float* __restrict__ bias,
    unsigned short* __restrict__ out,
    int Cout, int relu, const uint4* __restrict__ zp)
{
    constexpr int NM = BM / 16;
    constexpr int NN = (TW * TH) / 64;
    constexpr int Wf = 1 << LW, Hf = Wf;
    constexpr int WC = TW + 2, HR = TH + 2;
    constexpr int IN_GR = 4 * HR * WC;
    constexpr int LTW = (TW == 64) ? 6 : ((TW == 32) ? 5 : 7);
    constexpr int sH = UP ? (Hf >> 1) : Hf;
    constexpr int sW = UP ? (Wf >> 1) : Wf;
    __shared__ uint4 smem[IN_GR + 36 * BM];

    const int tid = threadIdx.x;
    const int lane = tid & 63, wv = tid >> 6;
    const int ng = Cout / BM;
    const int b = blockIdx.z / ng, cg = blockIdx.z % ng;
    const int x0 = blockIdx.x * TW, y0 = blockIdx.y * TH;
    const int NCK = (C1g + C2g) / 4;

    f32x4 acc[NM][NN];
#pragma unroll
    for (int m = 0; m < NM; ++m)
#pragma unroll
        for (int n = 0; n < NN; ++n) acc[m][n] = (f32x4){0.f, 0.f, 0.f, 0.f};

    const int l15 = lane & 15, l4 = lane >> 4;
    const int laneB = l4 * HR * WC + l15;
    const int laneA = l4 * BM + l15;

    for (int ck = 0; ck < NCK; ++ck) {
        if (ck) __syncthreads();
        {
            const uint4* src; int cg0, srcCg;
            if (ck * 4 < C1g) { src = in1; cg0 = ck * 4; srcCg = C1g; }
            else              { src = in2; cg0 = ck * 4 - C1g; srcCg = C2g; }
            for (int i = tid; i < IN_GR; i += 256) {
                int oct = i / (HR * WC);
                int rem = i - oct * (HR * WC);
                int row = rem / WC;
                int col = rem - row * WC;
                int gy = y0 + row - 1, gx = x0 + col - 1;
                int sy = UP ? (gy >> 1) : gy, sx = UP ? (gx >> 1) : gx;
                const uint4* ga = ((unsigned)gy < (unsigned)Hf && (unsigned)gx < (unsigned)Wf)
                    ? src + ((((size_t)b * sH + sy) * sW + sx) * srcCg + cg0 + oct)
                    : zp + (i & 63);
                lds_load16(ga, &smem[i]);
            }
        }
        {
            const uint4* wck = wt + (size_t)ck * 36 * Cout + (size_t)cg * BM;
            for (int i = tid; i < 36 * BM; i += 256) {
                int seg = i / BM, col = i - seg * BM;
                lds_load16(wck + seg * Cout + col, &smem[IN_GR + i]);
            }
        }
        __syncthreads();
        const half8* sB = (const half8*)smem;
        const half8* sA = (const half8*)(smem + IN_GR);
#pragma unroll
        for (int pos = 0; pos < 9; ++pos) {
            const int dr = pos / 3, dc = pos - dr * 3;
            half8 af[NM], bfr[NN];
#pragma unroll
            for (int m = 0; m < NM; ++m)
                af[m] = sA[pos * 4 * BM + m * 16 + laneA];
#pragma unroll
            for (int n = 0; n < NN; ++n) {
                const int pb = wv * (NN * 16) + n * 16;
                const int rn = (pb >> LTW) + dr;
                const int xn = (pb & (TW - 1)) + dc;
                bfr[n] = sB[rn * WC + xn + laneB];
            }
#pragma unroll
            for (int m = 0; m < NM; ++m)
#pragma unroll
                for (int n = 0; n < NN; ++n)
                    acc[m][n] = __builtin_amdgcn_mfma_f32_16x16x32_f16(af[m], bfr[n], acc[m][n], 0, 0, 0);
        }
    }

#pragma unroll
    for (int m = 0; m < NM; ++m) {
        const int co0 = cg * BM + m * 16 + l4 * 4;
        const float4 bs = *(const float4*)(bias + co0);
#pragma unroll
        for (int n = 0; n < NN; ++n) {
            const int pix = wv * (NN * 16) + n * 16 + l15;
            const int y = y0 + (pix >> LTW), x = x0 + (pix & (TW - 1));
            float v0 = acc[m][n][0] + bs.x;
            float v1 = acc[m][n][1] + bs.y;
            float v2 = acc[m][n][2] + bs.z;
            float v3 = acc[m][n][3] + bs.w;
            if (relu) {
                v0 = fmaxf(v0, 0.f); v1 = fmaxf(v1, 0.f);
                v2 = fmaxf(v2, 0.f); v3 = fmaxf(v3, 0.f);
            }
            uint2 pk;
            pk.x = (unsigned)f2h(v0) | ((unsigned)f2h(v1) << 16);
            pk.y = (unsigned)f2h(v2) | ((unsigned)f2h(v3) << 16);
            *(uint2*)(out + (((size_t)b * Hf + y) * Wf + x) * Cout + co0) = pk;
        }
    }
}

// ---- first conv 3->32, fp32 direct, NCHW fp32 in -> NHWC fp16 out ----
__global__ __launch_bounds__(256) void conv0_k(
    const float* __restrict__ in, const float* __restrict__ w,
    const float* __restrict__ bias, unsigned short* __restrict__ out)
{
    __shared__ float s_in[3][18][18];
    const int tx = threadIdx.x, ty = threadIdx.y;
    const int tid = ty * 16 + tx;
    const int b = blockIdx.z >> 2;
    const int coBase = (blockIdx.z & 3) * 8;
    const int bx = blockIdx.x * 16, by = blockIdx.y * 16;

    for (int i = tid; i < 3 * 18 * 18; i += 256) {
        int cc = i / 324, r = i % 324;
        int ly = r / 18, lx = r % 18;
        int gy = by + ly - 1, gx = bx + lx - 1;
        float v = 0.f;
        if ((unsigned)gy < 256u && (unsigned)gx < 256u)
            v = in[(((size_t)(b * 3 + cc)) << 16) + (gy << 8) + gx];
        ((float*)s_in)[i] = v;
    }
    __syncthreads();
    float acc[8];
#pragma unroll
    for (int k = 0; k < 8; ++k) acc[k] = 0.f;
    for (int cc = 0; cc < 3; ++cc) {
        float v[9];
#pragma unroll
        for (int dh = 0; dh < 3; ++dh)
#pragma unroll
            for (int dw = 0; dw < 3; ++dw)
                v[dh * 3 + dw] = s_in[cc][ty + dh][tx + dw];
        const float* wp = w + ((size_t)coBase * 3 + cc) * 9;
#pragma unroll
        for (int k = 0; k < 8; ++k) {
            const float* wk = wp + (size_t)k * 27;
            float a = acc[k];
#pragma unroll
            for (int j = 0; j < 9; ++j) a = fmaf(v[j], wk[j], a);
            acc[k] = a;
        }
    }
    const int h = by + ty, ww = bx + tx;
    unsigned short* op = out + (((size_t)(b * 256 + h)) * 256 + ww) * 32 + coBase;
#pragma unroll
    for (int k = 0; k < 8; ++k)
        op[k] = f2h(fmaxf(acc[k] + bias[coBase + k], 0.f));
}

// ---- 2x2 maxpool stride 2, NHWC fp16, 8 ch per thread ----
__global__ void poolh_k(const uint4* __restrict__ in, uint4* __restrict__ out,
                        int Ho, int Wo, int C8, int total)
{
    int i = blockIdx.x * 256 + threadIdx.x;
    if (i >= total) return;
    int oct = i % C8; int p = i / C8;
    int x = p % Wo; p /= Wo;
    int y = p % Ho; int b = p / Ho;
    const int H = Ho * 2, W = Wo * 2;
    size_t g = (((size_t)b * H + 2 * y) * W + 2 * x) * C8 + oct;
    uint4 v00 = in[g], v01 = in[g + C8];
    uint4 v10 = in[g + (size_t)W * C8], v11 = in[g + (size_t)W * C8 + C8];
    const unsigned short* a0 = (const unsigned short*)&v00;
    const unsigned short* a1 = (const unsigned short*)&v01;
    const unsigned short* a2 = (const unsigned short*)&v10;
    const unsigned short* a3 = (const unsigned short*)&v11;
    uint4 res; unsigned short* rp = (unsigned short*)&res;
#pragma unroll
    for (int j = 0; j < 8; ++j)
        rp[j] = f2h(fmaxf(fmaxf(h2f(a0[j]), h2f(a1[j])), fmaxf(h2f(a2[j]), h2f(a3[j]))));
    out[(((size_t)b * Ho + y) * Wo + x) * C8 + oct] = res;
}

// ---- fused 1x1 conv (32->32) + row inclusive scan -> integral-image rows ----
// block (y, b), 256 threads (one per x). Wave shuffle scan + cross-wave LDS.
__global__ __launch_bounds__(256) void rowprep_k(
    const uint4* __restrict__ in, const float* __restrict__ w,
    const float* __restrict__ bias, float* __restrict__ ii)
{
    __shared__ float sw[1024];
    __shared__ float sb[32];
    __shared__ float part[32][4];
    const int tid = threadIdx.x;
    const int lane = tid & 63, wv = tid >> 6;
    const int y = blockIdx.x, b = blockIdx.y;
    for (int i = tid; i < 1024; i += 256) sw[i] = w[i];
    if (tid < 32) sb[tid] = bias[tid];
    __syncthreads();

    // load 32 channels at (b, y, x)
    float xv[32];
    const uint4* ip = in + (((size_t)b * 256 + y) * 256 + tid) * 4;
#pragma unroll
    for (int q = 0; q < 4; ++q) {
        uint4 g = ip[q];
        const unsigned short* gs = (const unsigned short*)&g;
#pragma unroll
        for (int j = 0; j < 8; ++j) xv[q * 8 + j] = h2f(gs[j]);
    }
    // 1x1 conv
    float v[32];
#pragma unroll
    for (int co = 0; co < 32; ++co) {
        float a = sb[co];
#pragma unroll
        for (int ci = 0; ci < 32; ++ci) a = fmaf(xv[ci], sw[co * 32 + ci], a);
        v[co] = a;
    }
    // in-wave inclusive scan per channel
#pragma unroll
    for (int c = 0; c < 32; ++c) {
        float t = v[c];
#pragma unroll
        for (int off = 1; off < 64; off <<= 1) {
            float u = __shfl_up(t, off);
            if (lane >= off) t += u;
        }
        v[c] = t;
        if (lane == 63) part[c][wv] = t;
    }
    __syncthreads();
    // cross-wave prefixes + store
#pragma unroll
    for (int c = 0; c < 32; ++c) {
        float add = 0.f;
#pragma unroll
        for (int t = 0; t < 3; ++t)
            if (wv > t) add += part[c][t];
        float r = v[c] + add;
        float* plane = ii + (size_t)(b * 32 + c) * 66049;
        plane[(y + 1) * 257 + tid + 1] = r;
        if (tid == 0) plane[(y + 1) * 257] = 0.f;
        if (y == 0) {
            plane[tid + 1] = 0.f;
            if (tid == 0) plane[0] = 0.f;
        }
    }
}

// ---- segmented column scan: pass A (segment column sums) ----
__global__ __launch_bounds__(256) void colA_k(const float* __restrict__ ii,
                                              float* __restrict__ S)
{
    const int p = blockIdx.x, s = blockIdx.y;  // s in 0..2
    const int x = threadIdx.x;
    const float* plane = ii + (size_t)p * 66049;
    float acc = 0.f;
#pragma unroll 8
    for (int y = s * 64 + 1; y <= s * 64 + 64; ++y)
        acc += plane[(size_t)y * 257 + x + 1];
    S[(p * 3 + s) * 256 + x] = acc;
}

// ---- segmented column scan: pass B (apply prefixes, in-place scan) ----
__global__ __launch_bounds__(256) void colB_k(float* __restrict__ ii,
                                              const float* __restrict__ S)
{
    const int p = blockIdx.x, s = blockIdx.y;  // s in 0..3
    const int x = threadIdx.x;
    float* plane = ii + (size_t)p * 66049;
    float acc = 0.f;
    for (int t = 0; t < s; ++t) acc += S[(p * 3 + t) * 256 + x];
#pragma unroll 8
    for (int y = s * 64 + 1; y <= s * 64 + 64; ++y) {
        float* q = plane + (size_t)y * 257 + x + 1;
        acc += *q;
        *q = acc;
    }
}

// ---- adaptive ROI pool via integral image -> pooled[b][n][49] ----
__global__ void pool_k(const float* __restrict__ ii, const int* __restrict__ rois,
                       float* __restrict__ pooled)
{
    int t = blockIdx.x * 256 + threadIdx.x;  // < 8*1056*49
    int k = t % 49; int nb = t / 49;
    int n = nb % 1056; int b = nb / 1056;
    int ki = k / 7, kj = k % 7;
    int x1, y1, x2, y2, c;
    if (n < 32) {
        x1 = 0; y1 = 0; x2 = 256; y2 = 256; c = n;
    } else {
        int r = (n - 32) >> 5;
        c = (n - 32) & 31;
        x1 = rois[r * 4 + 0]; y1 = rois[r * 4 + 1];
        x2 = rois[r * 4 + 2]; y2 = rois[r * 4 + 3];
    }
    const int h = y2 - y1, w = x2 - x1;
    const int sy = y1 + (ki * h) / 7, ey = y1 + ((ki + 1) * h + 6) / 7;
    const int sx = x1 + (kj * w) / 7, ex = x1 + ((kj + 1) * w + 6) / 7;
    const float* pl = ii + (size_t)(b * 32 + c) * 66049;
    float s = pl[ey * 257 + ex] - pl[sy * 257 + ex] - pl[ey * 257 + sx] + pl[sy * 257 + sx];
    pooled[t] = s / (float)((ey - sy) * (ex - sx));
}

// ---- FC: out[b,n,f] = pooled[b,n,:] . fcwT[:,f] + fcb[f] ----
// block (nt, b): 16 n's, 512 threads (f). pooled reads are wave-uniform -> s_load.
__global__ __launch_bounds__(512) void fc_k(
    const float* __restrict__ pooled, const float* __restrict__ fcwT,
    const float* __restrict__ fcb, float* __restrict__ out)
{
    const int nt = blockIdx.x, b = blockIdx.y;
    const int f = threadIdx.x;
    float wr[49];
#pragma unroll
    for (int k = 0; k < 49; ++k) wr[k] = fcwT[k * 512 + f];
    const float base = fcb[f];
    const float* pr = pooled + ((size_t)b * 1056 + nt * 16) * 49;
    float* op = out + (((size_t)b * 1056 + nt * 16)) * 512 + f;
#pragma unroll
    for (int j = 0; j < 16; ++j) {
        float a = base;
#pragma unroll
        for (int k = 0; k < 49; ++k)
            a = fmaf(pr[j * 49 + k], wr[k], a);
        op[(size_t)j * 512] = a;
    }
}

extern "C" void kernel_launch(void* const* d_in, const int* in_sizes, int n_in,
                              void* d_out, int out_size, void* d_ws, size_t ws_size,
                              hipStream_t stream)
{
    const float* x    = (const float*)d_in[0];
    const int*   rois = (const int*)d_in[1];
    const float* e1w1 = (const float*)d_in[2];
    const float* e1b1 = (const float*)d_in[3];
    const float* e1w2 = (const float*)d_in[4];
    const float* e1b2 = (const float*)d_in[5];
    const float* e2w1 = (const float*)d_in[6];
    const float* e2b1 = (const float*)d_in[7];
    const float* e2w2 = (const float*)d_in[8];
    const float* e2b2 = (const float*)d_in[9];
    const float* bw1  = (const float*)d_in[10];
    const float* bb1  = (const float*)d_in[11];
    const float* bw2  = (const float*)d_in[12];
    const float* bb2  = (const float*)d_in[13];
    const float* u2w  = (const float*)d_in[14];
    const float* u2b  = (const float*)d_in[15];
    const float* d2w1 = (const float*)d_in[16];
    const float* d2b1 = (const float*)d_in[17];
    const float* d2w2 = (const float*)d_in[18];
    const float* d2b2 = (const float*)d_in[19];
    const float* u1w  = (const float*)d_in[20];
    const float* u1b  = (const float*)d_in[21];
    const float* d1w1 = (const float*)d_in[22];
    const float* d1b1 = (const float*)d_in[23];
    const float* d1w2 = (const float*)d_in[24];
    const float* d1b2 = (const float*)d_in[25];
    const float* fw   = (const float*)d_in[26];
    const float* fb   = (const float*)d_in[27];
    const float* fcw  = (const float*)d_in[28];
    const float* fcb  = (const float*)d_in[29];

    // ---- workspace: WT(4MB) A(33.5) D(16.8) E(16.8) B(33.5) C(8.4) F(67.6)
    char* wsb = (char*)d_ws;
    char* WT = wsb;
    char* A  = wsb + 4194304;
    char* D  = A + 33554432;
    char* E  = D + 16777216;
    char* Bb = E + 16777216;
    char* C  = Bb + 33554432;
    char* F  = C + 8388608;
    float* ii     = (float*)F;
    float* fcwT   = (float*)(WT + 1048576);        // 100 KB
    uint4* zp     = (uint4*)(WT + 4194304 - 8192); // zero page
    float* pooled = (float*)C;                     // 1.66 MB (C dead after bottleneck)
    float* Sbuf   = (float*)(C + 2097152);         // 786 KB
    hipMemsetAsync(zp, 0, 8192, stream);

    // ---- weight transforms ----
    const float* wsrc[11] = {e1w2, e2w1, e2w2, bw1, bw2, u2w, d2w1, d2w2, u1w, d1w1, d1w2};
    const int wco[11] = {32, 64, 64, 128, 128, 64, 64, 64, 32, 32, 32};
    const int wci[11] = {32, 32, 64, 64, 128, 128, 128, 64, 64, 64, 32};
    size_t woff[11]; size_t o = 0;
    for (int i = 0; i < 11; ++i) { woff[i] = o; o += (size_t)wco[i] * wci[i] * 18; }
    for (int i = 0; i < 11; ++i) {
        int total = wco[i] * wci[i] * 9;
        hipLaunchKernelGGL(wprep_k, dim3((total + 255) / 256), dim3(256), 0, stream,
                           wsrc[i], (unsigned short*)(WT + woff[i]), wco[i], wci[i], total);
    }
    hipLaunchKernelGGL(fct_k, dim3((49 * 512 + 255) / 256), dim3(256), 0, stream, fcw, fcwT);
    auto WP = [&](int i) { return (const uint4*)(WT + woff[i]); };

    #define CV1(i1,C1,i2,C2,wi,bs,ot,Cout,up,rl) \
        hipLaunchKernelGGL((convm2_k<32,64,8,8,up>), dim3(4,32,8*((Cout)/32)), dim3(256), 0, stream, \
            (const uint4*)(i1), (C1)/8, (const uint4*)(i2), (C2)/8, WP(wi), bs, \
            (unsigned short*)(ot), Cout, rl, zp)
    #define CV2(i1,C1,i2,C2,wi,bs,ot,Cout,up,rl) \
        hipLaunchKernelGGL((convm2_k<64,64,8,7,up>), dim3(2,16,8*((Cout)/64)), dim3(256), 0, stream, \
            (const uint4*)(i1), (C1)/8, (const uint4*)(i2), (C2)/8, WP(wi), bs, \
            (unsigned short*)(ot), Cout, rl, zp)
    #define CV3(i1,C1,i2,C2,wi,bs,ot,Cout,up,rl) \
        hipLaunchKernelGGL((convm2_k<64,64,4,6,up>), dim3(1,16,8*((Cout)/64)), dim3(256), 0, stream, \
            (const uint4*)(i1), (C1)/8, (const uint4*)(i2), (C2)/8, WP(wi), bs, \
            (unsigned short*)(ot), Cout, rl, zp)

    // encoder
    hipLaunchKernelGGL(conv0_k, dim3(16, 16, 32), dim3(16, 16), 0, stream,
                       x, e1w1, e1b1, (unsigned short*)A);        // e1a -> A
    CV1(A, 32, nullptr, 0, 0, e1b2, Bb, 32, 0, 1);               // e1  -> B
    {
        int N = 8 * 128 * 128 * 4;
        hipLaunchKernelGGL(poolh_k, dim3((N + 255) / 256), dim3(256), 0, stream,
                           (const uint4*)Bb, (uint4*)C, 128, 128, 4, N);  // p1 -> C
    }
    CV2(C, 32, nullptr, 0, 1, e2b1, A, 64, 0, 1);                // e2a -> A
    CV2(A, 64, nullptr, 0, 2, e2b2, D, 64, 0, 1);                // e2  -> D
    {
        int N = 8 * 64 * 64 * 8;
        hipLaunchKernelGGL(poolh_k, dim3((N + 255) / 256), dim3(256), 0, stream,
                           (const uint4*)D, (uint4*)C, 64, 64, 8, N);     // p2 -> C
    }
    // bottleneck
    CV3(C, 64, nullptr, 0, 3, bb1, E, 128, 0, 1);                // b1 -> E  (C free after)
    CV3(E, 128, nullptr, 0, 4, bb2, A, 128, 0, 1);               // b2 -> A
    // decoder level 2
    CV2(A, 128, nullptr, 0, 5, u2b, E, 64, 1, 1);                // u2 -> E (upsample)
    CV2(E, 64, D, 64, 6, d2b1, A, 64, 0, 1);                     // d2a -> A (concat)
    CV2(A, 64, nullptr, 0, 7, d2b2, D, 64, 0, 1);                // d2 -> D
    // decoder level 1
    CV1(D, 64, nullptr, 0, 8, u1b, A, 32, 1, 1);                 // u1 -> A (upsample)
    CV1(A, 32, Bb, 32, 9, d1b1, D, 32, 0, 1);                    // d1a -> D+E (concat)
    CV1(D, 32, nullptr, 0, 10, d1b2, Bb, 32, 0, 1);              // d1 -> B
    // fused 1x1 conv + row scan -> ii rows
    hipLaunchKernelGGL(rowprep_k, dim3(256, 8), dim3(256), 0, stream,
                       (const uint4*)Bb, fw, fb, ii);
    // segmented column scan
    hipLaunchKernelGGL(colA_k, dim3(256, 3), dim3(256), 0, stream, ii, Sbuf);
    hipLaunchKernelGGL(colB_k, dim3(256, 4), dim3(256), 0, stream, ii, Sbuf);
    // ROI pool + FC
    hipLaunchKernelGGL(pool_k, dim3(8 * 1056 * 49 / 256), dim3(256), 0, stream,
                       ii, rois, pooled);
    hipLaunchKernelGGL(fc_k, dim3(66, 8), dim3(512), 0, stream,
                       pooled, fcwT, fcb, (float*)d_out);
    #undef CV1
    #undef CV2
    #undef CV3
}

// Round 6
// 446.595 us; speedup vs baseline: 2.4329x; 2.4329x over previous
//
#include <hip/hip_runtime.h>

typedef _Float16 half8 __attribute__((ext_vector_type(8)));
typedef float f32x4 __attribute__((ext_vector_type(4)));

__device__ __forceinline__ unsigned short f2h(float f) {
    _Float16 h = (_Float16)f;
    return __builtin_bit_cast(unsigned short, h);
}
__device__ __forceinline__ float h2f(unsigned short u) {
    return (float)__builtin_bit_cast(_Float16, u);
}

// async global->LDS, 16 B per lane; LDS dest must be linear (base + lane*16)
__device__ __forceinline__ void lds_load16(const uint4* g, uint4* l) {
    __builtin_amdgcn_global_load_lds(
        (const __attribute__((address_space(1))) unsigned int*)g,
        (__attribute__((address_space(3))) unsigned int*)l, 16, 0, 0);
}

// ---- weight transform: OIHW fp32 -> [ck][pos][oct(ci/8)][co][ci&7] fp16 ----
__global__ void wprep_k(const float* __restrict__ src, unsigned short* __restrict__ dst,
                        int Cout, int Cin, int total)
{
    int t = blockIdx.x * 256 + threadIdx.x;
    if (t >= total) return;
    int j = t & 7; int r = t >> 3;
    int co = r % Cout; r /= Cout;
    int oct = r & 3; r >>= 2;
    int pos = r % 9; int ck = r / 9;
    int ci = ck * 32 + oct * 8 + j;
    dst[t] = f2h(src[((size_t)co * Cin + ci) * 9 + pos]);
}

// ---- fc weight transpose: fcw[f][k] -> fcwT[k][f] (512 x 49) ----
__global__ void fct_k(const float* __restrict__ src, float* __restrict__ dst)
{
    int t = blockIdx.x * 256 + threadIdx.x;
    if (t >= 49 * 512) return;
    int k = t >> 9, f = t & 511;
    dst[t] = src[f * 49 + k];
}

// ---- MFMA conv3x3 SAME, NHWC fp16, fp32 accum; 2D tiles, async staging ----
template<int BM, int TW, int TH, int LW, int UP>
__global__ __launch_bounds__(256, 2) void convm2_k(
    const uint4* __restrict__ in1, int C1g,
    const uint4* __restrict__ in2, int C2g,
    const uint4* __restrict__ wt,
    const float* __restrict__ bias,
    unsigned short* __restrict__ out,
    int Cout, int relu, const uint4* __restrict__ zp)
{
    constexpr int NM = BM / 16;
    constexpr int NN = (TW * TH) / 64;
    constexpr int Wf = 1 << LW, Hf = Wf;
    constexpr int WC = TW + 2, HR = TH + 2;
    constexpr int IN_GR = 4 * HR * WC;
    constexpr int LTW = (TW == 64) ? 6 : ((TW == 32) ? 5 : 7);
    constexpr int sH = UP ? (Hf >> 1) : Hf;
    constexpr int sW = UP ? (Wf >> 1) : Wf;
    __shared__ uint4 smem[IN_GR + 36 * BM];

    const int tid = threadIdx.x;
    const int lane = tid & 63, wv = tid >> 6;
    const int ng = Cout / BM;
    const int b = blockIdx.z / ng, cg = blockIdx.z % ng;
    const int x0 = blockIdx.x * TW, y0 = blockIdx.y * TH;
    const int NCK = (C1g + C2g) / 4;

    f32x4 acc[NM][NN];
#pragma unroll
    for (int m = 0; m < NM; ++m)
#pragma unroll
        for (int n = 0; n < NN; ++n) acc[m][n] = (f32x4){0.f, 0.f, 0.f, 0.f};

    const int l15 = lane & 15, l4 = lane >> 4;
    const int laneB = l4 * HR * WC + l15;
    const int laneA = l4 * BM + l15;

    for (int ck = 0; ck < NCK; ++ck) {
        if (ck) __syncthreads();
        {
            const uint4* src; int cg0, srcCg;
            if (ck * 4 < C1g) { src = in1; cg0 = ck * 4; srcCg = C1g; }
            else              { src = in2; cg0 = ck * 4 - C1g; srcCg = C2g; }
            for (int i = tid; i < IN_GR; i += 256) {
                int oct = i / (HR * WC);
                int rem = i - oct * (HR * WC);
                int row = rem / WC;
                int col = rem - row * WC;
                int gy = y0 + row - 1, gx = x0 + col - 1;
                int sy = UP ? (gy >> 1) : gy, sx = UP ? (gx >> 1) : gx;
                const uint4* ga = ((unsigned)gy < (unsigned)Hf && (unsigned)gx < (unsigned)Wf)
                    ? src + ((((size_t)b * sH + sy) * sW + sx) * srcCg + cg0 + oct)
                    : zp + (i & 63);
                lds_load16(ga, &smem[i]);
            }
        }
        {
            const uint4* wck = wt + (size_t)ck * 36 * Cout + (size_t)cg * BM;
            for (int i = tid; i < 36 * BM; i += 256) {
                int seg = i / BM, col = i - seg * BM;
                lds_load16(wck + seg * Cout + col, &smem[IN_GR + i]);
            }
        }
        __syncthreads();
        const half8* sB = (const half8*)smem;
        const half8* sA = (const half8*)(smem + IN_GR);
#pragma unroll
        for (int pos = 0; pos < 9; ++pos) {
            const int dr = pos / 3, dc = pos - dr * 3;
            half8 af[NM], bfr[NN];
#pragma unroll
            for (int m = 0; m < NM; ++m)
                af[m] = sA[pos * 4 * BM + m * 16 + laneA];
#pragma unroll
            for (int n = 0; n < NN; ++n) {
                const int pb = wv * (NN * 16) + n * 16;
                const int rn = (pb >> LTW) + dr;
                const int xn = (pb & (TW - 1)) + dc;
                bfr[n] = sB[rn * WC + xn + laneB];
            }
#pragma unroll
            for (int m = 0; m < NM; ++m)
#pragma unroll
                for (int n = 0; n < NN; ++n)
                    acc[m][n] = __builtin_amdgcn_mfma_f32_16x16x32_f16(af[m], bfr[n], acc[m][n], 0, 0, 0);
        }
    }

#pragma unroll
    for (int m = 0; m < NM; ++m) {
        const int co0 = cg * BM + m * 16 + l4 * 4;
        const float4 bs = *(const float4*)(bias + co0);
#pragma unroll
        for (int n = 0; n < NN; ++n) {
            const int pix = wv * (NN * 16) + n * 16 + l15;
            const int y = y0 + (pix >> LTW), x = x0 + (pix & (TW - 1));
            float v0 = acc[m][n][0] + bs.x;
            float v1 = acc[m][n][1] + bs.y;
            float v2 = acc[m][n][2] + bs.z;
            float v3 = acc[m][n][3] + bs.w;
            if (relu) {
                v0 = fmaxf(v0, 0.f); v1 = fmaxf(v1, 0.f);
                v2 = fmaxf(v2, 0.f); v3 = fmaxf(v3, 0.f);
            }
            uint2 pk;
            pk.x = (unsigned)f2h(v0) | ((unsigned)f2h(v1) << 16);
            pk.y = (unsigned)f2h(v2) | ((unsigned)f2h(v3) << 16);
            *(uint2*)(out + (((size_t)b * Hf + y) * Wf + x) * Cout + co0) = pk;
        }
    }
}

// ---- first conv 3->32, fp32 direct, NCHW fp32 in -> NHWC fp16 out ----
__global__ __launch_bounds__(256) void conv0_k(
    const float* __restrict__ in, const float* __restrict__ w,
    const float* __restrict__ bias, unsigned short* __restrict__ out)
{
    __shared__ float s_in[3][18][18];
    const int tx = threadIdx.x, ty = threadIdx.y;
    const int tid = ty * 16 + tx;
    const int b = blockIdx.z >> 2;
    const int coBase = (blockIdx.z & 3) * 8;
    const int bx = blockIdx.x * 16, by = blockIdx.y * 16;

    for (int i = tid; i < 3 * 18 * 18; i += 256) {
        int cc = i / 324, r = i % 324;
        int ly = r / 18, lx = r % 18;
        int gy = by + ly - 1, gx = bx + lx - 1;
        float v = 0.f;
        if ((unsigned)gy < 256u && (unsigned)gx < 256u)
            v = in[(((size_t)(b * 3 + cc)) << 16) + (gy << 8) + gx];
        ((float*)s_in)[i] = v;
    }
    __syncthreads();
    float acc[8];
#pragma unroll
    for (int k = 0; k < 8; ++k) acc[k] = 0.f;
    for (int cc = 0; cc < 3; ++cc) {
        float v[9];
#pragma unroll
        for (int dh = 0; dh < 3; ++dh)
#pragma unroll
            for (int dw = 0; dw < 3; ++dw)
                v[dh * 3 + dw] = s_in[cc][ty + dh][tx + dw];
        const float* wp = w + ((size_t)coBase * 3 + cc) * 9;
#pragma unroll
        for (int k = 0; k < 8; ++k) {
            const float* wk = wp + (size_t)k * 27;
            float a = acc[k];
#pragma unroll
            for (int j = 0; j < 9; ++j) a = fmaf(v[j], wk[j], a);
            acc[k] = a;
        }
    }
    const int h = by + ty, ww = bx + tx;
    unsigned short* op = out + (((size_t)(b * 256 + h)) * 256 + ww) * 32 + coBase;
#pragma unroll
    for (int k = 0; k < 8; ++k)
        op[k] = f2h(fmaxf(acc[k] + bias[coBase + k], 0.f));
}

// ---- 2x2 maxpool stride 2, NHWC fp16, 8 ch per thread ----
__global__ void poolh_k(const uint4* __restrict__ in, uint4* __restrict__ out,
                        int Ho, int Wo, int C8, int total)
{
    int i = blockIdx.x * 256 + threadIdx.x;
    if (i >= total) return;
    int oct = i % C8; int p = i / C8;
    int x = p % Wo; p /= Wo;
    int y = p % Ho; int b = p / Ho;
    const int H = Ho * 2, W = Wo * 2;
    size_t g = (((size_t)b * H + 2 * y) * W + 2 * x) * C8 + oct;
    uint4 v00 = in[g], v01 = in[g + C8];
    uint4 v10 = in[g + (size_t)W * C8], v11 = in[g + (size_t)W * C8 + C8];
    const unsigned short* a0 = (const unsigned short*)&v00;
    const unsigned short* a1 = (const unsigned short*)&v01;
    const unsigned short* a2 = (const unsigned short*)&v10;
    const unsigned short* a3 = (const unsigned short*)&v11;
    uint4 res; unsigned short* rp = (unsigned short*)&res;
#pragma unroll
    for (int j = 0; j < 8; ++j)
        rp[j] = f2h(fmaxf(fmaxf(h2f(a0[j]), h2f(a1[j])), fmaxf(h2f(a2[j]), h2f(a3[j]))));
    out[(((size_t)b * Ho + y) * Wo + x) * C8 + oct] = res;
}

// ---- fused 1x1 conv (32->32) + row inclusive scan -> integral-image rows ----
// block (y, b), 256 threads. Phase 1: conv one output channel at a time -> LDS
// (only xv[32] live; no spills). Phase 2: each wave scans 8 channel-rows
// independently (4 chunks of 64 px, lane-63 carry broadcast; no cross-wave comm).
__global__ __launch_bounds__(256) void rowprep_k(
    const uint4* __restrict__ in, const float* __restrict__ w,
    const float* __restrict__ bias, float* __restrict__ ii)
{
    __shared__ float sw[1024];
    __shared__ float sb[32];
    __shared__ float sout[32][256];
    const int tid = threadIdx.x;
    const int lane = tid & 63, wv = tid >> 6;
    const int y = blockIdx.x, b = blockIdx.y;
    for (int i = tid; i < 1024; i += 256) sw[i] = w[i];
    if (tid < 32) sb[tid] = bias[tid];
    __syncthreads();

    // load 32 channels at (b, y, x=tid)
    float xv[32];
    const uint4* ip = in + (((size_t)b * 256 + y) * 256 + tid) * 4;
#pragma unroll
    for (int q = 0; q < 4; ++q) {
        uint4 g = ip[q];
        const unsigned short* gs = (const unsigned short*)&g;
#pragma unroll
        for (int j = 0; j < 8; ++j) xv[q * 8 + j] = h2f(gs[j]);
    }
    // 1x1 conv, one co at a time -> LDS
#pragma unroll
    for (int co = 0; co < 32; ++co) {
        float a = sb[co];
#pragma unroll
        for (int ci = 0; ci < 32; ++ci) a = fmaf(xv[ci], sw[co * 32 + ci], a);
        sout[co][tid] = a;
    }
    __syncthreads();
    // zero the top border row once
    if (y == 0) {
        for (int i = tid; i < 32 * 257; i += 256) {
            int c = i / 257, xx = i % 257;
            ii[(size_t)(b * 32 + c) * 66049 + xx] = 0.f;
        }
    }
    // each wave scans 8 channels of this row
    for (int cc = 0; cc < 8; ++cc) {
        const int c = wv * 8 + cc;
        float* prow = ii + (size_t)(b * 32 + c) * 66049 + (size_t)(y + 1) * 257;
        if (lane == 0) prow[0] = 0.f;
        float carry = 0.f;
#pragma unroll
        for (int ch = 0; ch < 4; ++ch) {
            float v = sout[c][ch * 64 + lane];
#pragma unroll
            for (int off = 1; off < 64; off <<= 1) {
                float u = __shfl_up(v, off);
                if (lane >= off) v += u;
            }
            v += carry;
            prow[ch * 64 + lane + 1] = v;
            carry = __shfl(v, 63);
        }
    }
}

// ---- segmented column scan: pass A (segment column sums) ----
__global__ __launch_bounds__(256) void colA_k(const float* __restrict__ ii,
                                              float* __restrict__ S)
{
    const int p = blockIdx.x, s = blockIdx.y;  // s in 0..2
    const int x = threadIdx.x;
    const float* plane = ii + (size_t)p * 66049;
    float acc = 0.f;
#pragma unroll 8
    for (int y = s * 64 + 1; y <= s * 64 + 64; ++y)
        acc += plane[(size_t)y * 257 + x + 1];
    S[(p * 3 + s) * 256 + x] = acc;
}

// ---- segmented column scan: pass B (apply prefixes, in-place scan) ----
__global__ __launch_bounds__(256) void colB_k(float* __restrict__ ii,
                                              const float* __restrict__ S)
{
    const int p = blockIdx.x, s = blockIdx.y;  // s in 0..3
    const int x = threadIdx.x;
    float* plane = ii + (size_t)p * 66049;
    float acc = 0.f;
    for (int t = 0; t < s; ++t) acc += S[(p * 3 + t) * 256 + x];
#pragma unroll 8
    for (int y = s * 64 + 1; y <= s * 64 + 64; ++y) {
        float* q = plane + (size_t)y * 257 + x + 1;
        acc += *q;
        *q = acc;
    }
}

// ---- adaptive ROI pool via integral image -> pooled[b][n][49] ----
__global__ void pool_k(const float* __restrict__ ii, const int* __restrict__ rois,
                       float* __restrict__ pooled)
{
    int t = blockIdx.x * 256 + threadIdx.x;  // < 8*1056*49
    int k = t % 49; int nb = t / 49;
    int n = nb % 1056; int b = nb / 1056;
    int ki = k / 7, kj = k % 7;
    int x1, y1, x2, y2, c;
    if (n < 32) {
        x1 = 0; y1 = 0; x2 = 256; y2 = 256; c = n;
    } else {
        int r = (n - 32) >> 5;
        c = (n - 32) & 31;
        x1 = rois[r * 4 + 0]; y1 = rois[r * 4 + 1];
        x2 = rois[r * 4 + 2]; y2 = rois[r * 4 + 3];
    }
    const int h = y2 - y1, w = x2 - x1;
    const int sy = y1 + (ki * h) / 7, ey = y1 + ((ki + 1) * h + 6) / 7;
    const int sx = x1 + (kj * w) / 7, ex = x1 + ((kj + 1) * w + 6) / 7;
    const float* pl = ii + (size_t)(b * 32 + c) * 66049;
    float s = pl[ey * 257 + ex] - pl[sy * 257 + ex] - pl[ey * 257 + sx] + pl[sy * 257 + sx];
    pooled[t] = s / (float)((ey - sy) * (ex - sx));
}

// ---- FC: out[b,n,f] = pooled[b,n,:] . fcwT[:,f] + fcb[f] ----
__global__ __launch_bounds__(512) void fc_k(
    const float* __restrict__ pooled, const float* __restrict__ fcwT,
    const float* __restrict__ fcb, float* __restrict__ out)
{
    const int nt = blockIdx.x, b = blockIdx.y;
    const int f = threadIdx.x;
    float wr[49];
#pragma unroll
    for (int k = 0; k < 49; ++k) wr[k] = fcwT[k * 512 + f];
    const float base = fcb[f];
    const float* pr = pooled + ((size_t)b * 1056 + nt * 16) * 49;
    float* op = out + (((size_t)b * 1056 + nt * 16)) * 512 + f;
#pragma unroll
    for (int j = 0; j < 16; ++j) {
        float a = base;
#pragma unroll
        for (int k = 0; k < 49; ++k)
            a = fmaf(pr[j * 49 + k], wr[k], a);
        op[(size_t)j * 512] = a;
    }
}

extern "C" void kernel_launch(void* const* d_in, const int* in_sizes, int n_in,
                              void* d_out, int out_size, void* d_ws, size_t ws_size,
                              hipStream_t stream)
{
    const float* x    = (const float*)d_in[0];
    const int*   rois = (const int*)d_in[1];
    const float* e1w1 = (const float*)d_in[2];
    const float* e1b1 = (const float*)d_in[3];
    const float* e1w2 = (const float*)d_in[4];
    const float* e1b2 = (const float*)d_in[5];
    const float* e2w1 = (const float*)d_in[6];
    const float* e2b1 = (const float*)d_in[7];
    const float* e2w2 = (const float*)d_in[8];
    const float* e2b2 = (const float*)d_in[9];
    const float* bw1  = (const float*)d_in[10];
    const float* bb1  = (const float*)d_in[11];
    const float* bw2  = (const float*)d_in[12];
    const float* bb2  = (const float*)d_in[13];
    const float* u2w  = (const float*)d_in[14];
    const float* u2b  = (const float*)d_in[15];
    const float* d2w1 = (const float*)d_in[16];
    const float* d2b1 = (const float*)d_in[17];
    const float* d2w2 = (const float*)d_in[18];
    const float* d2b2 = (const float*)d_in[19];
    const float* u1w  = (const float*)d_in[20];
    const float* u1b  = (const float*)d_in[21];
    const float* d1w1 = (const float*)d_in[22];
    const float* d1b1 = (const float*)d_in[23];
    const float* d1w2 = (const float*)d_in[24];
    const float* d1b2 = (const float*)d_in[25];
    const float* fw   = (const float*)d_in[26];
    const float* fb   = (const float*)d_in[27];
    const float* fcw  = (const float*)d_in[28];
    const float* fcb  = (const float*)d_in[29];

    // ---- workspace: WT(4MB) A(33.5) D(16.8) E(16.8) B(33.5) C(8.4) F(67.6)
    char* wsb = (char*)d_ws;
    char* WT = wsb;
    char* A  = wsb + 4194304;
    char* D  = A + 33554432;
    char* E  = D + 16777216;
    char* Bb = E + 16777216;
    char* C  = Bb + 33554432;
    char* F  = C + 8388608;
    float* ii     = (float*)F;
    float* fcwT   = (float*)(WT + 1048576);        // 100 KB
    uint4* zp     = (uint4*)(WT + 4194304 - 8192); // zero page
    float* pooled = (float*)C;                     // 1.66 MB (C dead after bottleneck)
    float* Sbuf   = (float*)(C + 2097152);         // 786 KB
    hipMemsetAsync(zp, 0, 8192, stream);

    // ---- weight transforms ----
    const float* wsrc[11] = {e1w2, e2w1, e2w2, bw1, bw2, u2w, d2w1, d2w2, u1w, d1w1, d1w2};
    const int wco[11] = {32, 64, 64, 128, 128, 64, 64, 64, 32, 32, 32};
    const int wci[11] = {32, 32, 64, 64, 128, 128, 128, 64, 64, 64, 32};
    size_t woff[11]; size_t o = 0;
    for (int i = 0; i < 11; ++i) { woff[i] = o; o += (size_t)wco[i] * wci[i] * 18; }
    for (int i = 0; i < 11; ++i) {
        int total = wco[i] * wci[i] * 9;
        hipLaunchKernelGGL(wprep_k, dim3((total + 255) / 256), dim3(256), 0, stream,
                           wsrc[i], (unsigned short*)(WT + woff[i]), wco[i], wci[i], total);
    }
    hipLaunchKernelGGL(fct_k, dim3((49 * 512 + 255) / 256), dim3(256), 0, stream, fcw, fcwT);
    auto WP = [&](int i) { return (const uint4*)(WT + woff[i]); };

    #define CV1(i1,C1,i2,C2,wi,bs,ot,Cout,up,rl) \
        hipLaunchKernelGGL((convm2_k<32,64,8,8,up>), dim3(4,32,8*((Cout)/32)), dim3(256), 0, stream, \
            (const uint4*)(i1), (C1)/8, (const uint4*)(i2), (C2)/8, WP(wi), bs, \
            (unsigned short*)(ot), Cout, rl, zp)
    #define CV2(i1,C1,i2,C2,wi,bs,ot,Cout,up,rl) \
        hipLaunchKernelGGL((convm2_k<64,64,8,7,up>), dim3(2,16,8*((Cout)/64)), dim3(256), 0, stream, \
            (const uint4*)(i1), (C1)/8, (const uint4*)(i2), (C2)/8, WP(wi), bs, \
            (unsigned short*)(ot), Cout, rl, zp)
    #define CV3(i1,C1,i2,C2,wi,bs,ot,Cout,up,rl) \
        hipLaunchKernelGGL((convm2_k<64,64,4,6,up>), dim3(1,16,8*((Cout)/64)), dim3(256), 0, stream, \
            (const uint4*)(i1), (C1)/8, (const uint4*)(i2), (C2)/8, WP(wi), bs, \
            (unsigned short*)(ot), Cout, rl, zp)

    // encoder
    hipLaunchKernelGGL(conv0_k, dim3(16, 16, 32), dim3(16, 16), 0, stream,
                       x, e1w1, e1b1, (unsigned short*)A);        // e1a -> A
    CV1(A, 32, nullptr, 0, 0, e1b2, Bb, 32, 0, 1);               // e1  -> B
    {
        int N = 8 * 128 * 128 * 4;
        hipLaunchKernelGGL(poolh_k, dim3((N + 255) / 256), dim3(256), 0, stream,
                           (const uint4*)Bb, (uint4*)C, 128, 128, 4, N);  // p1 -> C
    }
    CV2(C, 32, nullptr, 0, 1, e2b1, A, 64, 0, 1);                // e2a -> A
    CV2(A, 64, nullptr, 0, 2, e2b2, D, 64, 0, 1);                // e2  -> D
    {
        int N = 8 * 64 * 64 * 8;
        hipLaunchKernelGGL(poolh_k, dim3((N + 255) / 256), dim3(256), 0, stream,
                           (const uint4*)D, (uint4*)C, 64, 64, 8, N);     // p2 -> C
    }
    // bottleneck
    CV3(C, 64, nullptr, 0, 3, bb1, E, 128, 0, 1);                // b1 -> E  (C free after)
    CV3(E, 128, nullptr, 0, 4, bb2, A, 128, 0, 1);               // b2 -> A
    // decoder level 2
    CV2(A, 128, nullptr, 0, 5, u2b, E, 64, 1, 1);                // u2 -> E (upsample)
    CV2(E, 64, D, 64, 6, d2b1, A, 64, 0, 1);                     // d2a -> A (concat)
    CV2(A, 64, nullptr, 0, 7, d2b2, D, 64, 0, 1);                // d2 -> D
    // decoder level 1
    CV1(D, 64, nullptr, 0, 8, u1b, A, 32, 1, 1);                 // u1 -> A (upsample)
    CV1(A, 32, Bb, 32, 9, d1b1, D, 32, 0, 1);                    // d1a -> D+E (concat)
    CV1(D, 32, nullptr, 0, 10, d1b2, Bb, 32, 0, 1);              // d1 -> B
    // fused 1x1 conv + row scan -> ii rows
    hipLaunchKernelGGL(rowprep_k, dim3(256, 8), dim3(256), 0, stream,
                       (const uint4*)Bb, fw, fb, ii);
    // segmented column scan
    hipLaunchKernelGGL(colA_k, dim3(256, 3), dim3(256), 0, stream, ii, Sbuf);
    hipLaunchKernelGGL(colB_k, dim3(256, 4), dim3(256), 0, stream, ii, Sbuf);
    // ROI pool + FC
    hipLaunchKernelGGL(pool_k, dim3(8 * 1056 * 49 / 256), dim3(256), 0, stream,
                       ii, rois, pooled);
    hipLaunchKernelGGL(fc_k, dim3(66, 8), dim3(512), 0, stream,
                       pooled, fcwT, fcb, (float*)d_out);
    #undef CV1
    #undef CV2
    #undef CV3
}